// Round 12
// baseline (459.366 us; speedup 1.0000x reference)
//
#include <hip/hip_runtime.h>

#define NN 20000
#define FF 128
#define HH 128
#define LL 4
#define OO 64
#define EE 640000
#define NEG 0.2f
#define NB ((NN + 255) / 256)   // 79 scan blocks
#define NTILES (NN / 16)        // 1250

typedef short bf16x8 __attribute__((ext_vector_type(8)));
typedef float f32x4 __attribute__((ext_vector_type(4)));

__device__ inline ushort f2bf(float f) {  // f32 -> bf16 RNE
    uint u = __float_as_uint(f);
    return (ushort)((u + 0x7fffu + ((u >> 16) & 1u)) >> 16);
}

// ---------------- CSR build (dst-grouped, launch-invariant) ----------------

__global__ void k_init_counters(int* __restrict__ counters) {
    int i = blockIdx.x * 256 + threadIdx.x;
    if (i < NN) counters[i] = 1;  // self-loop pre-counted
}

__global__ void k_hist(const int* __restrict__ dst, int* __restrict__ counters) {
    int e = blockIdx.x * 256 + threadIdx.x;
    if (e < EE) atomicAdd(&counters[dst[e]], 1);
}

__global__ void k_partial(const int* __restrict__ counters, int* __restrict__ partials) {
    __shared__ int ws[4];
    int t = threadIdx.x;
    int i = blockIdx.x * 256 + t;
    int c = (i < NN) ? counters[i] : 0;
    #pragma unroll
    for (int off = 32; off; off >>= 1) c += __shfl_xor(c, off);
    if ((t & 63) == 0) ws[t >> 6] = c;
    __syncthreads();
    if (t == 0) partials[blockIdx.x] = ws[0] + ws[1] + ws[2] + ws[3];
}

__global__ void k_scan_small(const int* __restrict__ partials, int* __restrict__ offsets) {
    __shared__ int sp[128];
    int t = threadIdx.x;
    int v = (t < NB) ? partials[t] : 0;
    sp[t] = v;
    __syncthreads();
    for (int off = 1; off < 128; off <<= 1) {
        int u = (t >= off) ? sp[t - off] : 0;
        __syncthreads();
        sp[t] += u;
        __syncthreads();
    }
    if (t < NB) offsets[t] = sp[t] - v;  // exclusive
}

__global__ void k_apply(const int* __restrict__ counters, const int* __restrict__ offsets,
                        int* __restrict__ row_off, int* __restrict__ cursor,
                        int* __restrict__ src_sorted) {
    __shared__ int sc[256];
    int t = threadIdx.x;
    int i = blockIdx.x * 256 + t;
    int c = (i < NN) ? counters[i] : 0;
    sc[t] = c;
    __syncthreads();
    for (int off = 1; off < 256; off <<= 1) {
        int u = (t >= off) ? sc[t - off] : 0;
        __syncthreads();
        sc[t] += u;
        __syncthreads();
    }
    int incl = sc[t];
    int base = offsets[blockIdx.x];
    if (i < NN) {
        int excl = base + incl - c;
        row_off[i] = excl;
        cursor[i] = excl + 1;       // slot 0 taken by self-loop
        src_sorted[excl] = i;       // self-loop edge first
        if (i == NN - 1) row_off[NN] = base + incl;
    }
}

__global__ void k_scatter(const int* __restrict__ src, const int* __restrict__ dst,
                          int* __restrict__ cursor, int* __restrict__ src_sorted) {
    int e = blockIdx.x * 256 + threadIdx.x;
    if (e < EE) {
        int p = atomicAdd(&cursor[dst[e]], 1);
        src_sorted[p] = src[e];
    }
}

// ---------------- W conversion: f32 [k][n] -> bf16 hi/lo transposed [n][k] ----------------

__global__ void k_convw(const float* __restrict__ Ws, const float* __restrict__ Wout,
                        ushort* __restrict__ wh, ushort* __restrict__ wl) {
    int idx = blockIdx.x * 256 + threadIdx.x;
    const int per_l = HH * 128;
    float v;
    if (idx < LL * per_l) {
        int l = idx / per_l, rem = idx % per_l;
        int n = rem >> 7, k = rem & 127;
        v = Ws[(size_t)l * 128 * HH + (size_t)k * HH + n];
    } else {
        int j = idx - LL * per_l;
        if (j >= OO * 128) return;
        int n = j >> 7, k = j & 127;
        v = Wout[(size_t)k * OO + n];
    }
    ushort h = f2bf(v);
    float hf = __uint_as_float((uint)h << 16);
    wh[idx] = h;
    wl[idx] = f2bf(v - hf);
}

// ---------------- wa precompute: wa[l][0][k] = (W_l @ a_s)[k]; [1][k] for a_d ----

__global__ void k_wa(const float* __restrict__ Ws, const float* __restrict__ attS,
                     const float* __restrict__ attD, float* __restrict__ wa) {
    int t = blockIdx.x * 256 + threadIdx.x;
    if (t >= LL * 256) return;
    int l = t >> 8, rem = t & 255, which = rem >> 7, k = rem & 127;
    const float* wrow = Ws + (size_t)l * 128 * HH + (size_t)k * HH;
    const float* av = (which ? attD : attS) + l * HH;
    float s = 0.f;
    #pragma unroll 4
    for (int n = 0; n < HH; n++) s += wrow[n] * av[n];
    wa[l * 256 + which * 128 + k] = s;
}

// ---------------- agg: quarter-split gather (z quarter = 2.56MB, L2-resident) ----------------
// zq layout: [q][node][32] f32. Wave lanes: c4 = l&7 (float4 within quarter),
// ep = l>>3 (8 parallel edges). Per node, per quarter q: loop edges stride 8,
// 2-deep unroll (16 edges in flight); reduce acc/s over ep via shfl_xor 8/16/32.

__device__ inline void do_agg(const float* __restrict__ zq, const float* __restrict__ asv,
                              const float* __restrict__ adv, const int* __restrict__ row_off,
                              const int* __restrict__ srcs, const float* __restrict__ bias,
                              float (*h)[132], int node0, int wid, int l64) {
    int c4 = l64 & 7, ep = l64 >> 3;
    #pragma unroll 1
    for (int i = 0; i < 2; i++) {
        int node = node0 + wid * 2 + i;
        int beg = row_off[node], end = row_off[node + 1];
        float adn = adv[node];
        float lself = asv[node] + adn;
        float mx = (lself >= 0.f) ? lself : NEG * lself;  // self edge slot 0 -> p_self=1
        int lrow = wid * 2 + i;

        #pragma unroll 1
        for (int q = 0; q < 4; q++) {
            const float* qbase = zq + (size_t)q * NN * 32;
            float4 acc = make_float4(0.f, 0.f, 0.f, 0.f);
            float s = 0.f;
            for (int e = beg + ep; e < end; e += 16) {  // edges e, e+8
                int lim = end - 1;
                int i1 = min(e + 8, lim);
                int s0 = srcs[e], s1 = srcs[i1];
                float l0 = asv[s0] + adn, l1 = asv[s1] + adn;
                l0 = (l0 >= 0.f) ? l0 : NEG * l0;
                l1 = (l1 >= 0.f) ? l1 : NEG * l1;
                float4 z0 = *(const float4*)(qbase + (size_t)s0 * 32 + c4 * 4);
                float4 z1 = *(const float4*)(qbase + (size_t)s1 * 32 + c4 * 4);
                float p0 = __expf(l0 - mx);
                float p1 = (e + 8 < end) ? __expf(l1 - mx) : 0.f;
                s += p0 + p1;
                acc.x += p0 * z0.x + p1 * z1.x;
                acc.y += p0 * z0.y + p1 * z1.y;
                acc.z += p0 * z0.z + p1 * z1.z;
                acc.w += p0 * z0.w + p1 * z1.w;
            }
            // reduce over ep (lane bits 3..5); all lanes in an ep-group hold equal s
            acc.x += __shfl_xor(acc.x, 8);
            acc.y += __shfl_xor(acc.y, 8);
            acc.z += __shfl_xor(acc.z, 8);
            acc.w += __shfl_xor(acc.w, 8);
            s     += __shfl_xor(s, 8);
            acc.x += __shfl_xor(acc.x, 16);
            acc.y += __shfl_xor(acc.y, 16);
            acc.z += __shfl_xor(acc.z, 16);
            acc.w += __shfl_xor(acc.w, 16);
            s     += __shfl_xor(s, 16);
            acc.x += __shfl_xor(acc.x, 32);
            acc.y += __shfl_xor(acc.y, 32);
            acc.z += __shfl_xor(acc.z, 32);
            acc.w += __shfl_xor(acc.w, 32);
            s     += __shfl_xor(s, 32);
            if (ep == 0) {
                float inv = 1.f / (s + 1e-16f);
                float4 b = ((const float4*)bias)[q * 8 + c4];
                float4 o;
                o.x = fmaxf(acc.x * inv + b.x, 0.f);
                o.y = fmaxf(acc.y * inv + b.y, 0.f);
                o.z = fmaxf(acc.z * inv + b.z, 0.f);
                o.w = fmaxf(acc.w * inv + b.w, 0.f);
                *(float4*)&h[lrow][q * 32 + c4 * 4] = o;
            }
        }
    }
}

// ---------------- GEMM: 8 waves x 16-col tiles (NCOL=128) / 4 waves (NCOL=64) ----------------
// PACKED: write channels into quarter-major zq + alphas into as_o/ad_o.

template <int NCOL, bool BIAS, bool ALPHAS, bool PACKED>
__device__ inline void do_gemm(const float (*h)[132], const ushort* __restrict__ wh,
                               const ushort* __restrict__ wl, const float* __restrict__ bias,
                               float* __restrict__ C, const float* __restrict__ wa,
                               float* __restrict__ as_o, float* __restrict__ ad_o,
                               int row0, int wid, int l64) {
    constexpr int CT = NCOL / 16;
    if (wid >= CT) return;   // idle waves (no sync below)
    int lr = l64 & 15, lg = l64 >> 4;
    int col0 = wid * 16;

    f32x4 af0[4], af1[4];
    #pragma unroll
    for (int s = 0; s < 4; s++) {
        af0[s] = *(const f32x4*)&h[lr][s * 32 + lg * 8];
        af1[s] = *(const f32x4*)&h[lr][s * 32 + lg * 8 + 4];
    }
    bf16x8 ah[4], al[4];
    #pragma unroll
    for (int s = 0; s < 4; s++) {
        #pragma unroll
        for (int j = 0; j < 8; j++) {
            float v = (j < 4) ? af0[s][j] : af1[s][j - 4];
            ushort hb = f2bf(v);
            float hf = __uint_as_float((uint)hb << 16);
            ah[s][j] = (short)hb;
            al[s][j] = (short)f2bf(v - hf);
        }
    }

    f32x4 acc = {0.f, 0.f, 0.f, 0.f};
    #pragma unroll
    for (int s = 0; s < 4; s++) {
        int woff = (col0 + lr) * 128 + s * 32 + lg * 8;
        bf16x8 bh = *(const bf16x8*)(wh + woff);
        bf16x8 bl = *(const bf16x8*)(wl + woff);
        acc = __builtin_amdgcn_mfma_f32_16x16x32_bf16(ah[s], bh, acc, 0, 0, 0);
        acc = __builtin_amdgcn_mfma_f32_16x16x32_bf16(ah[s], bl, acc, 0, 0, 0);
        acc = __builtin_amdgcn_mfma_f32_16x16x32_bf16(al[s], bh, acc, 0, 0, 0);
    }

    int orow = lg * 4;
    int c = col0 + lr;
    #pragma unroll
    for (int r = 0; r < 4; r++) {
        float v = acc[r];
        if (BIAS) v += bias[c];
        if (PACKED)
            C[((size_t)(c >> 5) * NN + (row0 + orow + r)) * 32 + (c & 31)] = v;
        else
            C[(size_t)(row0 + orow + r) * NCOL + c] = v;
    }

    if constexpr (ALPHAS) {
        if (wid == 0) {
            float ps = 0.f, pd = 0.f;
            #pragma unroll
            for (int s = 0; s < 4; s++) {
                #pragma unroll
                for (int j = 0; j < 8; j++) {
                    float v = (j < 4) ? af0[s][j] : af1[s][j - 4];
                    int k = s * 32 + lg * 8 + j;
                    ps += v * wa[k];
                    pd += v * wa[128 + k];
                }
            }
            ps += __shfl_xor(ps, 16);  pd += __shfl_xor(pd, 16);
            ps += __shfl_xor(ps, 32);  pd += __shfl_xor(pd, 32);
            if (lg == 0) {
                as_o[row0 + lr] = ps;
                ad_o[row0 + lr] = pd;
            }
        }
    }
}

// ---------------- layer kernels (grid = 1250, block = 512 / 8 waves) ----------------

__global__ __launch_bounds__(512)
void k_layer0(const float* __restrict__ x, const ushort* __restrict__ wh,
              const ushort* __restrict__ wl, const float* __restrict__ wa,
              float* __restrict__ zq, float* __restrict__ as_o, float* __restrict__ ad_o) {
    __shared__ float h[16][132];
    int t = threadIdx.x, wid = t >> 6, l64 = t & 63;
    int row0 = blockIdx.x * 16;
    {   // stage x tile (16 x 128 f32 = 512 float4, one per thread)
        int r = t >> 5, c4 = (t & 31) << 2;
        *(float4*)&h[r][c4] = *(const float4*)&x[(size_t)(row0 + r) * 128 + c4];
    }
    __syncthreads();
    do_gemm<HH, false, true, true>(h, wh, wl, nullptr, zq, wa, as_o, ad_o, row0, wid, l64);
}

template <int NCOL, bool BIAS, bool ALPHAS, bool PACKED>
__global__ __launch_bounds__(512)
void k_layer(const float* __restrict__ zin, const float* __restrict__ asi,
             const float* __restrict__ adi, const int* __restrict__ row_off,
             const int* __restrict__ srcs, const float* __restrict__ abias,
             const ushort* __restrict__ wh, const ushort* __restrict__ wl,
             const float* __restrict__ cbias, const float* __restrict__ wa,
             float* __restrict__ zout, float* __restrict__ as_o, float* __restrict__ ad_o) {
    __shared__ float h[16][132];
    int t = threadIdx.x, wid = t >> 6, l64 = t & 63;
    int row0 = blockIdx.x * 16;
    do_agg(zin, asi, adi, row_off, srcs, abias, h, row0, wid, l64);
    __syncthreads();
    do_gemm<NCOL, BIAS, ALPHAS, PACKED>(h, wh, wl, cbias, zout, wa, as_o, ad_o,
                                        row0, wid, l64);
}

// ---------------- launch ----------------

extern "C" void kernel_launch(void* const* d_in, const int* in_sizes, int n_in,
                              void* d_out, int out_size, void* d_ws, size_t ws_size,
                              hipStream_t stream) {
    const float* x      = (const float*)d_in[0];
    const int*   ei     = (const int*)d_in[1];
    const float* Ws     = (const float*)d_in[2];
    const float* attS   = (const float*)d_in[3];
    const float* attD   = (const float*)d_in[4];
    const float* biases = (const float*)d_in[5];
    const float* W_out  = (const float*)d_in[6];
    const float* b_out  = (const float*)d_in[7];
    float* out = (float*)d_out;

    const int* srcp = ei;
    const int* dstp = ei + EE;

    char* w = (char*)d_ws;
    auto take = [&](size_t bytes) {
        char* p = w;
        w += (bytes + 15) & ~(size_t)15;
        return p;
    };
    float*  zqa        = (float*)take((size_t)NN * 128 * 4);
    float*  zqb        = (float*)take((size_t)NN * 128 * 4);
    float*  asa        = (float*)take((size_t)NN * 4);
    float*  ada        = (float*)take((size_t)NN * 4);
    float*  asb        = (float*)take((size_t)NN * 4);
    float*  adb        = (float*)take((size_t)NN * 4);
    int*    counters   = (int*)take((size_t)NN * 4);
    int*    row_off    = (int*)take((size_t)(NN + 1) * 4);
    int*    cursor     = (int*)take((size_t)NN * 4);
    int*    src_sorted = (int*)take((size_t)(EE + NN) * 4);
    int*    partials   = (int*)take((size_t)NB * 4);
    int*    offsets    = (int*)take((size_t)NB * 4);
    const int WTOT = LL * HH * 128 + OO * 128;   // 73728
    ushort* whbuf      = (ushort*)take((size_t)WTOT * 2);
    ushort* wlbuf      = (ushort*)take((size_t)WTOT * 2);
    float*  wabuf      = (float*)take((size_t)LL * 256 * 4);

    // CSR build + weight prep
    k_init_counters<<<(NN + 255) / 256, 256, 0, stream>>>(counters);
    k_hist<<<(EE + 255) / 256, 256, 0, stream>>>(dstp, counters);
    k_partial<<<NB, 256, 0, stream>>>(counters, partials);
    k_scan_small<<<1, 128, 0, stream>>>(partials, offsets);
    k_apply<<<NB, 256, 0, stream>>>(counters, offsets, row_off, cursor, src_sorted);
    k_scatter<<<(EE + 255) / 256, 256, 0, stream>>>(srcp, dstp, cursor, src_sorted);
    k_convw<<<(WTOT + 255) / 256, 256, 0, stream>>>(Ws, W_out, whbuf, wlbuf);
    k_wa<<<(LL * 256 + 255) / 256, 256, 0, stream>>>(Ws, attS, attD, wabuf);

    // layer 0: z0 = x @ W0 (+alphas)
    k_layer0<<<NTILES, 512, 0, stream>>>(x, whbuf, wlbuf, wabuf, zqa, asa, ada);

    // layers 1..3: agg + gemm (+alphas), quarter-major z double-buffer
    k_layer<HH, false, true, true><<<NTILES, 512, 0, stream>>>(
        zqa, asa, ada, row_off, src_sorted, biases + 0 * HH,
        whbuf + (size_t)1 * HH * 128, wlbuf + (size_t)1 * HH * 128,
        nullptr, wabuf + 1 * 256, zqb, asb, adb);
    k_layer<HH, false, true, true><<<NTILES, 512, 0, stream>>>(
        zqb, asb, adb, row_off, src_sorted, biases + 1 * HH,
        whbuf + (size_t)2 * HH * 128, wlbuf + (size_t)2 * HH * 128,
        nullptr, wabuf + 2 * 256, zqa, asa, ada);
    k_layer<HH, false, true, true><<<NTILES, 512, 0, stream>>>(
        zqa, asa, ada, row_off, src_sorted, biases + 2 * HH,
        whbuf + (size_t)3 * HH * 128, wlbuf + (size_t)3 * HH * 128,
        nullptr, wabuf + 3 * 256, zqb, asb, adb);

    // final: agg(z3) + out-projection with bias (raw [N][64] output)
    k_layer<OO, true, false, false><<<NTILES, 512, 0, stream>>>(
        zqb, asb, adb, row_off, src_sorted, biases + 3 * HH,
        whbuf + (size_t)LL * HH * 128, wlbuf + (size_t)LL * HH * 128,
        b_out, nullptr, out, nullptr, nullptr);
}

// Round 13
// 377.154 us; speedup vs baseline: 1.2180x; 1.2180x over previous
//
#include <hip/hip_runtime.h>

#define NN 20000
#define FF 128
#define HH 128
#define LL 4
#define OO 64
#define EE 640000
#define NEG 0.2f
#define NB ((NN + 255) / 256)   // 79 scan blocks
#define NTILES (NN / 16)        // 1250

typedef short bf16x8 __attribute__((ext_vector_type(8)));
typedef float f32x4 __attribute__((ext_vector_type(4)));

__device__ inline ushort f2bf(float f) {  // f32 -> bf16 RNE
    uint u = __float_as_uint(f);
    return (ushort)((u + 0x7fffu + ((u >> 16) & 1u)) >> 16);
}

// ---------------- CSR build (dst-grouped, launch-invariant) ----------------

__global__ void k_init_counters(int* __restrict__ counters) {
    int i = blockIdx.x * 256 + threadIdx.x;
    if (i < NN) counters[i] = 1;  // self-loop pre-counted
}

__global__ void k_hist(const int* __restrict__ dst, int* __restrict__ counters) {
    int e = blockIdx.x * 256 + threadIdx.x;
    if (e < EE) atomicAdd(&counters[dst[e]], 1);
}

__global__ void k_partial(const int* __restrict__ counters, int* __restrict__ partials) {
    __shared__ int ws[4];
    int t = threadIdx.x;
    int i = blockIdx.x * 256 + t;
    int c = (i < NN) ? counters[i] : 0;
    #pragma unroll
    for (int off = 32; off; off >>= 1) c += __shfl_xor(c, off);
    if ((t & 63) == 0) ws[t >> 6] = c;
    __syncthreads();
    if (t == 0) partials[blockIdx.x] = ws[0] + ws[1] + ws[2] + ws[3];
}

__global__ void k_scan_small(const int* __restrict__ partials, int* __restrict__ offsets) {
    __shared__ int sp[128];
    int t = threadIdx.x;
    int v = (t < NB) ? partials[t] : 0;
    sp[t] = v;
    __syncthreads();
    for (int off = 1; off < 128; off <<= 1) {
        int u = (t >= off) ? sp[t - off] : 0;
        __syncthreads();
        sp[t] += u;
        __syncthreads();
    }
    if (t < NB) offsets[t] = sp[t] - v;  // exclusive
}

__global__ void k_apply(const int* __restrict__ counters, const int* __restrict__ offsets,
                        int* __restrict__ row_off, int* __restrict__ cursor,
                        int* __restrict__ src_sorted) {
    __shared__ int sc[256];
    int t = threadIdx.x;
    int i = blockIdx.x * 256 + t;
    int c = (i < NN) ? counters[i] : 0;
    sc[t] = c;
    __syncthreads();
    for (int off = 1; off < 256; off <<= 1) {
        int u = (t >= off) ? sc[t - off] : 0;
        __syncthreads();
        sc[t] += u;
        __syncthreads();
    }
    int incl = sc[t];
    int base = offsets[blockIdx.x];
    if (i < NN) {
        int excl = base + incl - c;
        row_off[i] = excl;
        cursor[i] = excl + 1;       // slot 0 taken by self-loop
        src_sorted[excl] = i;       // self-loop edge first
        if (i == NN - 1) row_off[NN] = base + incl;
    }
}

__global__ void k_scatter(const int* __restrict__ src, const int* __restrict__ dst,
                          int* __restrict__ cursor, int* __restrict__ src_sorted) {
    int e = blockIdx.x * 256 + threadIdx.x;
    if (e < EE) {
        int p = atomicAdd(&cursor[dst[e]], 1);
        src_sorted[p] = src[e];
    }
}

// ---------------- W conversion: f32 [k][n] -> bf16 hi/lo transposed [n][k] ----------------

__global__ void k_convw(const float* __restrict__ Ws, const float* __restrict__ Wout,
                        ushort* __restrict__ wh, ushort* __restrict__ wl) {
    int idx = blockIdx.x * 256 + threadIdx.x;
    const int per_l = HH * 128;
    float v;
    if (idx < LL * per_l) {
        int l = idx / per_l, rem = idx % per_l;
        int n = rem >> 7, k = rem & 127;
        v = Ws[(size_t)l * 128 * HH + (size_t)k * HH + n];
    } else {
        int j = idx - LL * per_l;
        if (j >= OO * 128) return;
        int n = j >> 7, k = j & 127;
        v = Wout[(size_t)k * OO + n];
    }
    ushort h = f2bf(v);
    float hf = __uint_as_float((uint)h << 16);
    wh[idx] = h;
    wl[idx] = f2bf(v - hf);
}

// ---------------- wa precompute: wa[l][0][k] = (W_l @ a_s)[k]; [1][k] for a_d ----

__global__ void k_wa(const float* __restrict__ Ws, const float* __restrict__ attS,
                     const float* __restrict__ attD, float* __restrict__ wa) {
    int t = blockIdx.x * 256 + threadIdx.x;
    if (t >= LL * 256) return;
    int l = t >> 8, rem = t & 255, which = rem >> 7, k = rem & 127;
    const float* wrow = Ws + (size_t)l * 128 * HH + (size_t)k * HH;
    const float* av = (which ? attD : attS) + l * HH;
    float s = 0.f;
    #pragma unroll 4
    for (int n = 0; n < HH; n++) s += wrow[n] * av[n];
    wa[l * 256 + which * 128 + k] = s;
}

// ---------------- agg: 1 wave per node (R8-proven form), writes h row in LDS ----------------
// z row-major [N][128] f32; separate as/ad arrays. 2 lane-groups x 8-deep predicated
// unroll = 16 edges in flight per wave. Shift = self-loop logit (slot 0).

__device__ inline void do_agg1(const float* __restrict__ z, const float* __restrict__ asv,
                               const float* __restrict__ adv, const int* __restrict__ row_off,
                               const int* __restrict__ srcs, const float* __restrict__ bias,
                               float (*h)[132], int node, int lrow, int l64) {
    int g = l64 >> 5, cl = l64 & 31;
    const float4* zb = (const float4*)z;   // row stride = 32 float4
    int beg = row_off[node], end = row_off[node + 1];
    float adn = adv[node];
    float lself = asv[node] + adn;
    float mx = (lself >= 0.f) ? lself : NEG * lself;  // self edge slot 0 -> p_self=1

    float4 acc = make_float4(0.f, 0.f, 0.f, 0.f);
    float s = 0.f;
    for (int e = beg + g; e < end; e += 16) {
        int e1 = e + 2, e2 = e + 4, e3 = e + 6, e4 = e + 8, e5 = e + 10, e6 = e + 12, e7 = e + 14;
        int lim = end - 1;
        int i1 = min(e1, lim), i2 = min(e2, lim), i3 = min(e3, lim);
        int i4 = min(e4, lim), i5 = min(e5, lim), i6 = min(e6, lim), i7 = min(e7, lim);
        int s0 = srcs[e], s1 = srcs[i1], s2 = srcs[i2], s3 = srcs[i3];
        int s4 = srcs[i4], s5 = srcs[i5], s6 = srcs[i6], s7 = srcs[i7];
        float l0 = asv[s0] + adn, l1 = asv[s1] + adn, l2 = asv[s2] + adn, l3 = asv[s3] + adn;
        float l4 = asv[s4] + adn, l5 = asv[s5] + adn, l6 = asv[s6] + adn, l7 = asv[s7] + adn;
        l0 = (l0 >= 0.f) ? l0 : NEG * l0;  l1 = (l1 >= 0.f) ? l1 : NEG * l1;
        l2 = (l2 >= 0.f) ? l2 : NEG * l2;  l3 = (l3 >= 0.f) ? l3 : NEG * l3;
        l4 = (l4 >= 0.f) ? l4 : NEG * l4;  l5 = (l5 >= 0.f) ? l5 : NEG * l5;
        l6 = (l6 >= 0.f) ? l6 : NEG * l6;  l7 = (l7 >= 0.f) ? l7 : NEG * l7;
        float4 z0 = zb[(size_t)s0 * 32 + cl];
        float4 z1 = zb[(size_t)s1 * 32 + cl];
        float4 z2 = zb[(size_t)s2 * 32 + cl];
        float4 z3 = zb[(size_t)s3 * 32 + cl];
        float4 z4 = zb[(size_t)s4 * 32 + cl];
        float4 z5 = zb[(size_t)s5 * 32 + cl];
        float4 z6 = zb[(size_t)s6 * 32 + cl];
        float4 z7 = zb[(size_t)s7 * 32 + cl];
        float p0 = __expf(l0 - mx);
        float p1 = (e1 < end) ? __expf(l1 - mx) : 0.f;
        float p2 = (e2 < end) ? __expf(l2 - mx) : 0.f;
        float p3 = (e3 < end) ? __expf(l3 - mx) : 0.f;
        float p4 = (e4 < end) ? __expf(l4 - mx) : 0.f;
        float p5 = (e5 < end) ? __expf(l5 - mx) : 0.f;
        float p6 = (e6 < end) ? __expf(l6 - mx) : 0.f;
        float p7 = (e7 < end) ? __expf(l7 - mx) : 0.f;
        s += ((p0 + p1) + (p2 + p3)) + ((p4 + p5) + (p6 + p7));
        acc.x += (p0 * z0.x + p1 * z1.x + p2 * z2.x + p3 * z3.x)
               + (p4 * z4.x + p5 * z5.x + p6 * z6.x + p7 * z7.x);
        acc.y += (p0 * z0.y + p1 * z1.y + p2 * z2.y + p3 * z3.y)
               + (p4 * z4.y + p5 * z5.y + p6 * z6.y + p7 * z7.y);
        acc.z += (p0 * z0.z + p1 * z1.z + p2 * z2.z + p3 * z3.z)
               + (p4 * z4.z + p5 * z5.z + p6 * z6.z + p7 * z7.z);
        acc.w += (p0 * z0.w + p1 * z1.w + p2 * z2.w + p3 * z3.w)
               + (p4 * z4.w + p5 * z5.w + p6 * z6.w + p7 * z7.w);
    }
    acc.x += __shfl_xor(acc.x, 32);
    acc.y += __shfl_xor(acc.y, 32);
    acc.z += __shfl_xor(acc.z, 32);
    acc.w += __shfl_xor(acc.w, 32);
    s     += __shfl_xor(s, 32);
    if (g == 0) {
        float inv = 1.f / (s + 1e-16f);
        float4 b = ((const float4*)bias)[cl];
        h[lrow][cl * 4 + 0] = fmaxf(acc.x * inv + b.x, 0.f);
        h[lrow][cl * 4 + 1] = fmaxf(acc.y * inv + b.y, 0.f);
        h[lrow][cl * 4 + 2] = fmaxf(acc.z * inv + b.z, 0.f);
        h[lrow][cl * 4 + 3] = fmaxf(acc.w * inv + b.w, 0.f);
    }
}

// ---------------- GEMM from LDS h: waves wid < NCOL/16, 16-col tile each ----------------

template <int NCOL, bool BIAS, bool ALPHAS>
__device__ inline void do_gemm(const float (*h)[132], const ushort* __restrict__ wh,
                               const ushort* __restrict__ wl, const float* __restrict__ bias,
                               float* __restrict__ C, const float* __restrict__ wa,
                               float* __restrict__ as_o, float* __restrict__ ad_o,
                               int row0, int wid, int l64) {
    constexpr int CT = NCOL / 16;
    if (wid >= CT) return;   // idle waves (no sync below)
    int lr = l64 & 15, lg = l64 >> 4;
    int col0 = wid * 16;

    f32x4 af0[4], af1[4];
    #pragma unroll
    for (int s = 0; s < 4; s++) {
        af0[s] = *(const f32x4*)&h[lr][s * 32 + lg * 8];
        af1[s] = *(const f32x4*)&h[lr][s * 32 + lg * 8 + 4];
    }
    bf16x8 ah[4], al[4];
    #pragma unroll
    for (int s = 0; s < 4; s++) {
        #pragma unroll
        for (int j = 0; j < 8; j++) {
            float v = (j < 4) ? af0[s][j] : af1[s][j - 4];
            ushort hb = f2bf(v);
            float hf = __uint_as_float((uint)hb << 16);
            ah[s][j] = (short)hb;
            al[s][j] = (short)f2bf(v - hf);
        }
    }

    f32x4 acc = {0.f, 0.f, 0.f, 0.f};
    #pragma unroll
    for (int s = 0; s < 4; s++) {
        int woff = (col0 + lr) * 128 + s * 32 + lg * 8;
        bf16x8 bh = *(const bf16x8*)(wh + woff);
        bf16x8 bl = *(const bf16x8*)(wl + woff);
        acc = __builtin_amdgcn_mfma_f32_16x16x32_bf16(ah[s], bh, acc, 0, 0, 0);
        acc = __builtin_amdgcn_mfma_f32_16x16x32_bf16(ah[s], bl, acc, 0, 0, 0);
        acc = __builtin_amdgcn_mfma_f32_16x16x32_bf16(al[s], bh, acc, 0, 0, 0);
    }

    int orow = lg * 4;
    int c = col0 + lr;
    #pragma unroll
    for (int r = 0; r < 4; r++) {
        float v = acc[r];
        if (BIAS) v += bias[c];
        C[(size_t)(row0 + orow + r) * NCOL + c] = v;
    }

    if constexpr (ALPHAS) {
        if (wid == 0) {
            float ps = 0.f, pd = 0.f;
            #pragma unroll
            for (int s = 0; s < 4; s++) {
                #pragma unroll
                for (int j = 0; j < 8; j++) {
                    float v = (j < 4) ? af0[s][j] : af1[s][j - 4];
                    int k = s * 32 + lg * 8 + j;
                    ps += v * wa[k];
                    pd += v * wa[128 + k];
                }
            }
            ps += __shfl_xor(ps, 16);  pd += __shfl_xor(pd, 16);
            ps += __shfl_xor(ps, 32);  pd += __shfl_xor(pd, 32);
            if (lg == 0) {
                as_o[row0 + lr] = ps;
                ad_o[row0 + lr] = pd;
            }
        }
    }
}

// ---------------- layer kernels ----------------

// layer 0: no agg; 512 thr (8 waves) suffices for the gemm
__global__ __launch_bounds__(512)
void k_layer0(const float* __restrict__ x, const ushort* __restrict__ wh,
              const ushort* __restrict__ wl, const float* __restrict__ wa,
              float* __restrict__ z, float* __restrict__ as_o, float* __restrict__ ad_o) {
    __shared__ float h[16][132];
    int t = threadIdx.x, wid = t >> 6, l64 = t & 63;
    int row0 = blockIdx.x * 16;
    {   // stage x tile (16 x 128 f32 = 512 float4, one per thread)
        int r = t >> 5, c4 = (t & 31) << 2;
        *(float4*)&h[r][c4] = *(const float4*)&x[(size_t)(row0 + r) * 128 + c4];
    }
    __syncthreads();
    do_gemm<HH, false, true>(h, wh, wl, nullptr, z, wa, as_o, ad_o, row0, wid, l64);
}

// layers 1..4: 1024 thr (16 waves) — agg = 1 wave per node (full R8 concurrency),
// then 8 (or 4) waves run the in-LDS gemm.
template <int NCOL, bool BIAS, bool ALPHAS>
__global__ __launch_bounds__(1024)
void k_layer(const float* __restrict__ zin, const float* __restrict__ asi,
             const float* __restrict__ adi, const int* __restrict__ row_off,
             const int* __restrict__ srcs, const float* __restrict__ abias,
             const ushort* __restrict__ wh, const ushort* __restrict__ wl,
             const float* __restrict__ cbias, const float* __restrict__ wa,
             float* __restrict__ zout, float* __restrict__ as_o, float* __restrict__ ad_o) {
    __shared__ float h[16][132];
    int t = threadIdx.x, wid = t >> 6, l64 = t & 63;
    int row0 = blockIdx.x * 16;
    do_agg1(zin, asi, adi, row_off, srcs, abias, h, row0 + wid, wid, l64);
    __syncthreads();
    do_gemm<NCOL, BIAS, ALPHAS>(h, wh, wl, cbias, zout, wa, as_o, ad_o, row0, wid, l64);
}

// ---------------- launch ----------------

extern "C" void kernel_launch(void* const* d_in, const int* in_sizes, int n_in,
                              void* d_out, int out_size, void* d_ws, size_t ws_size,
                              hipStream_t stream) {
    const float* x      = (const float*)d_in[0];
    const int*   ei     = (const int*)d_in[1];
    const float* Ws     = (const float*)d_in[2];
    const float* attS   = (const float*)d_in[3];
    const float* attD   = (const float*)d_in[4];
    const float* biases = (const float*)d_in[5];
    const float* W_out  = (const float*)d_in[6];
    const float* b_out  = (const float*)d_in[7];
    float* out = (float*)d_out;

    const int* srcp = ei;
    const int* dstp = ei + EE;

    char* w = (char*)d_ws;
    auto take = [&](size_t bytes) {
        char* p = w;
        w += (bytes + 15) & ~(size_t)15;
        return p;
    };
    float*  za         = (float*)take((size_t)NN * HH * 4);
    float*  zbv        = (float*)take((size_t)NN * HH * 4);
    float*  asa        = (float*)take((size_t)NN * 4);
    float*  ada        = (float*)take((size_t)NN * 4);
    float*  asb        = (float*)take((size_t)NN * 4);
    float*  adb        = (float*)take((size_t)NN * 4);
    int*    counters   = (int*)take((size_t)NN * 4);
    int*    row_off    = (int*)take((size_t)(NN + 1) * 4);
    int*    cursor     = (int*)take((size_t)NN * 4);
    int*    src_sorted = (int*)take((size_t)(EE + NN) * 4);
    int*    partials   = (int*)take((size_t)NB * 4);
    int*    offsets    = (int*)take((size_t)NB * 4);
    const int WTOT = LL * HH * 128 + OO * 128;   // 73728
    ushort* whbuf      = (ushort*)take((size_t)WTOT * 2);
    ushort* wlbuf      = (ushort*)take((size_t)WTOT * 2);
    float*  wabuf      = (float*)take((size_t)LL * 256 * 4);

    // CSR build + weight prep
    k_init_counters<<<(NN + 255) / 256, 256, 0, stream>>>(counters);
    k_hist<<<(EE + 255) / 256, 256, 0, stream>>>(dstp, counters);
    k_partial<<<NB, 256, 0, stream>>>(counters, partials);
    k_scan_small<<<1, 128, 0, stream>>>(partials, offsets);
    k_apply<<<NB, 256, 0, stream>>>(counters, offsets, row_off, cursor, src_sorted);
    k_scatter<<<(EE + 255) / 256, 256, 0, stream>>>(srcp, dstp, cursor, src_sorted);
    k_convw<<<(WTOT + 255) / 256, 256, 0, stream>>>(Ws, W_out, whbuf, wlbuf);
    k_wa<<<(LL * 256 + 255) / 256, 256, 0, stream>>>(Ws, attS, attD, wabuf);

    // layer 0: z0 = x @ W0 (+alphas)
    k_layer0<<<NTILES, 512, 0, stream>>>(x, whbuf, wlbuf, wabuf, za, asa, ada);

    // layers 1..3: agg + gemm (+alphas), z double-buffer
    k_layer<HH, false, true><<<NTILES, 1024, 0, stream>>>(
        za, asa, ada, row_off, src_sorted, biases + 0 * HH,
        whbuf + (size_t)1 * HH * 128, wlbuf + (size_t)1 * HH * 128,
        nullptr, wabuf + 1 * 256, zbv, asb, adb);
    k_layer<HH, false, true><<<NTILES, 1024, 0, stream>>>(
        zbv, asb, adb, row_off, src_sorted, biases + 1 * HH,
        whbuf + (size_t)2 * HH * 128, wlbuf + (size_t)2 * HH * 128,
        nullptr, wabuf + 2 * 256, za, asa, ada);
    k_layer<HH, false, true><<<NTILES, 1024, 0, stream>>>(
        za, asa, ada, row_off, src_sorted, biases + 2 * HH,
        whbuf + (size_t)3 * HH * 128, wlbuf + (size_t)3 * HH * 128,
        nullptr, wabuf + 3 * 256, zbv, asb, adb);

    // final: agg(z3) + out-projection with bias
    k_layer<OO, true, false><<<NTILES, 1024, 0, stream>>>(
        zbv, asb, adb, row_off, src_sorted, biases + 3 * HH,
        whbuf + (size_t)LL * HH * 128, wlbuf + (size_t)LL * HH * 128,
        b_out, nullptr, out, nullptr, nullptr);
}

// Round 14
// 317.882 us; speedup vs baseline: 1.4451x; 1.1865x over previous
//
#include <hip/hip_runtime.h>

#define NN 20000
#define FF 128
#define HH 128
#define LL 4
#define OO 64
#define EE 640000
#define ET (EE + NN)            // total edges incl self-loops
#define NEG 0.2f
#define NB ((NN + 255) / 256)   // 79 scan blocks
#define NTILES (NN / 16)        // 1250

typedef short bf16x8 __attribute__((ext_vector_type(8)));
typedef float f32x4 __attribute__((ext_vector_type(4)));

__device__ inline ushort f2bf(float f) {  // f32 -> bf16 RNE
    uint u = __float_as_uint(f);
    return (ushort)((u + 0x7fffu + ((u >> 16) & 1u)) >> 16);
}

// ---------------- CSR build (dst-grouped, launch-invariant) ----------------

__global__ void k_init_counters(int* __restrict__ counters) {
    int i = blockIdx.x * 256 + threadIdx.x;
    if (i < NN) counters[i] = 1;  // self-loop pre-counted
}

__global__ void k_hist(const int* __restrict__ dst, int* __restrict__ counters) {
    int e = blockIdx.x * 256 + threadIdx.x;
    if (e < EE) atomicAdd(&counters[dst[e]], 1);
}

__global__ void k_partial(const int* __restrict__ counters, int* __restrict__ partials) {
    __shared__ int ws[4];
    int t = threadIdx.x;
    int i = blockIdx.x * 256 + t;
    int c = (i < NN) ? counters[i] : 0;
    #pragma unroll
    for (int off = 32; off; off >>= 1) c += __shfl_xor(c, off);
    if ((t & 63) == 0) ws[t >> 6] = c;
    __syncthreads();
    if (t == 0) partials[blockIdx.x] = ws[0] + ws[1] + ws[2] + ws[3];
}

__global__ void k_scan_small(const int* __restrict__ partials, int* __restrict__ offsets) {
    __shared__ int sp[128];
    int t = threadIdx.x;
    int v = (t < NB) ? partials[t] : 0;
    sp[t] = v;
    __syncthreads();
    for (int off = 1; off < 128; off <<= 1) {
        int u = (t >= off) ? sp[t - off] : 0;
        __syncthreads();
        sp[t] += u;
        __syncthreads();
    }
    if (t < NB) offsets[t] = sp[t] - v;  // exclusive
}

__global__ void k_apply(const int* __restrict__ counters, const int* __restrict__ offsets,
                        int* __restrict__ row_off, int* __restrict__ cursor,
                        int* __restrict__ src_sorted, int* __restrict__ dst_sorted) {
    __shared__ int sc[256];
    int t = threadIdx.x;
    int i = blockIdx.x * 256 + t;
    int c = (i < NN) ? counters[i] : 0;
    sc[t] = c;
    __syncthreads();
    for (int off = 1; off < 256; off <<= 1) {
        int u = (t >= off) ? sc[t - off] : 0;
        __syncthreads();
        sc[t] += u;
        __syncthreads();
    }
    int incl = sc[t];
    int base = offsets[blockIdx.x];
    if (i < NN) {
        int excl = base + incl - c;
        row_off[i] = excl;
        cursor[i] = excl + 1;       // slot 0 taken by self-loop
        src_sorted[excl] = i;       // self-loop edge first
        dst_sorted[excl] = i;
        if (i == NN - 1) row_off[NN] = base + incl;
    }
}

__global__ void k_scatter(const int* __restrict__ src, const int* __restrict__ dst,
                          int* __restrict__ cursor, int* __restrict__ src_sorted,
                          int* __restrict__ dst_sorted) {
    int e = blockIdx.x * 256 + threadIdx.x;
    if (e < EE) {
        int d = dst[e];
        int pidx = atomicAdd(&cursor[d], 1);
        src_sorted[pidx] = src[e];
        dst_sorted[pidx] = d;
    }
}

// ---------------- W conversion: f32 [k][n] -> bf16 hi/lo transposed [n][k] ----------------

__global__ void k_convw(const float* __restrict__ Ws, const float* __restrict__ Wout,
                        ushort* __restrict__ wh, ushort* __restrict__ wl) {
    int idx = blockIdx.x * 256 + threadIdx.x;
    const int per_l = HH * 128;
    float v;
    if (idx < LL * per_l) {
        int l = idx / per_l, rem = idx % per_l;
        int n = rem >> 7, k = rem & 127;
        v = Ws[(size_t)l * 128 * HH + (size_t)k * HH + n];
    } else {
        int j = idx - LL * per_l;
        if (j >= OO * 128) return;
        int n = j >> 7, k = j & 127;
        v = Wout[(size_t)k * OO + n];
    }
    ushort h = f2bf(v);
    float hf = __uint_as_float((uint)h << 16);
    wh[idx] = h;
    wl[idx] = f2bf(v - hf);
}

// ---------------- wa precompute: wa[l][0][k] = (W_l @ a_s)[k]; [1][k] for a_d ----

__global__ void k_wa(const float* __restrict__ Ws, const float* __restrict__ attS,
                     const float* __restrict__ attD, float* __restrict__ wa) {
    int t = blockIdx.x * 256 + threadIdx.x;
    if (t >= LL * 256) return;
    int l = t >> 8, rem = t & 255, which = rem >> 7, k = rem & 127;
    const float* wrow = Ws + (size_t)l * 128 * HH + (size_t)k * HH;
    const float* av = (which ? attD : attS) + l * HH;
    float s = 0.f;
    #pragma unroll 4
    for (int n = 0; n < HH; n++) s += wrow[n] * av[n];
    wa[l * 256 + which * 128 + k] = s;
}

// ---------------- edge weights: p[e] = exp(leaky(as[src]+ad[dst]) - leaky(as[dst]+ad[dst])) --
// as/ad are 80KB arrays (L2-resident); reads/writes of srcs/dsts/p coalesced.
// Self-loop edge: src==dst -> p = 1 exactly (same shift as before -> identical numerics).

__global__ void k_ew(const float* __restrict__ asv, const float* __restrict__ adv,
                     const int* __restrict__ srcs, const int* __restrict__ dsts,
                     float* __restrict__ p) {
    int e = blockIdx.x * 256 + threadIdx.x;
    if (e >= ET) return;
    int s = srcs[e], d = dsts[e];
    float ad_ = adv[d];
    float ls = asv[s] + ad_;  ls = (ls >= 0.f) ? ls : NEG * ls;
    float ld = asv[d] + ad_;  ld = (ld >= 0.f) ? ld : NEG * ld;
    p[e] = __expf(ls - ld);
}

// ---------------- agg: wave per node, pure p*z gather-FMA (p precomputed) ----------------
// 256-thr blocks, 4 nodes/block (5000 blocks). Lane-group g takes contiguous 8-edge
// runs (p/srcs loads merge); 16 edges in flight. h = relu(acc/s + bias) -> global.

__global__ __launch_bounds__(256)
void k_agg(const float* __restrict__ z, const float* __restrict__ p,
           const int* __restrict__ row_off, const int* __restrict__ srcs,
           const float* __restrict__ bias, float* __restrict__ h) {
    int node = blockIdx.x * 4 + (threadIdx.x >> 6);
    int l64 = threadIdx.x & 63;
    if (node >= NN) return;
    int g = l64 >> 5, cl = l64 & 31;
    int beg = row_off[node], end = row_off[node + 1], lim = end - 1;
    const float4* zb = (const float4*)z;

    float4 acc = make_float4(0.f, 0.f, 0.f, 0.f);
    float s = 0.f;
    for (int e = beg + g * 8; e < end; e += 16) {
        int i1 = min(e + 1, lim), i2 = min(e + 2, lim), i3 = min(e + 3, lim);
        int i4 = min(e + 4, lim), i5 = min(e + 5, lim), i6 = min(e + 6, lim), i7 = min(e + 7, lim);
        int s0 = srcs[e],  s1 = srcs[i1], s2 = srcs[i2], s3 = srcs[i3];
        int s4 = srcs[i4], s5 = srcs[i5], s6 = srcs[i6], s7 = srcs[i7];
        float p0 = p[e];
        float p1 = (e + 1 < end) ? p[e + 1] : 0.f;
        float p2 = (e + 2 < end) ? p[e + 2] : 0.f;
        float p3 = (e + 3 < end) ? p[e + 3] : 0.f;
        float p4 = (e + 4 < end) ? p[e + 4] : 0.f;
        float p5 = (e + 5 < end) ? p[e + 5] : 0.f;
        float p6 = (e + 6 < end) ? p[e + 6] : 0.f;
        float p7 = (e + 7 < end) ? p[e + 7] : 0.f;
        float4 z0 = zb[(size_t)s0 * 32 + cl];
        float4 z1 = zb[(size_t)s1 * 32 + cl];
        float4 z2 = zb[(size_t)s2 * 32 + cl];
        float4 z3 = zb[(size_t)s3 * 32 + cl];
        float4 z4 = zb[(size_t)s4 * 32 + cl];
        float4 z5 = zb[(size_t)s5 * 32 + cl];
        float4 z6 = zb[(size_t)s6 * 32 + cl];
        float4 z7 = zb[(size_t)s7 * 32 + cl];
        s += ((p0 + p1) + (p2 + p3)) + ((p4 + p5) + (p6 + p7));
        acc.x += (p0 * z0.x + p1 * z1.x + p2 * z2.x + p3 * z3.x)
               + (p4 * z4.x + p5 * z5.x + p6 * z6.x + p7 * z7.x);
        acc.y += (p0 * z0.y + p1 * z1.y + p2 * z2.y + p3 * z3.y)
               + (p4 * z4.y + p5 * z5.y + p6 * z6.y + p7 * z7.y);
        acc.z += (p0 * z0.z + p1 * z1.z + p2 * z2.z + p3 * z3.z)
               + (p4 * z4.z + p5 * z5.z + p6 * z6.z + p7 * z7.z);
        acc.w += (p0 * z0.w + p1 * z1.w + p2 * z2.w + p3 * z3.w)
               + (p4 * z4.w + p5 * z5.w + p6 * z6.w + p7 * z7.w);
    }

    acc.x += __shfl_xor(acc.x, 32);
    acc.y += __shfl_xor(acc.y, 32);
    acc.z += __shfl_xor(acc.z, 32);
    acc.w += __shfl_xor(acc.w, 32);
    s     += __shfl_xor(s, 32);

    if (g == 0) {
        float inv = 1.f / (s + 1e-16f);
        float4 b = ((const float4*)bias)[cl];
        float4 o;
        o.x = fmaxf(acc.x * inv + b.x, 0.f);
        o.y = fmaxf(acc.y * inv + b.y, 0.f);
        o.z = fmaxf(acc.z * inv + b.z, 0.f);
        o.w = fmaxf(acc.w * inv + b.w, 0.f);
        ((float4*)h)[(size_t)node * 32 + cl] = o;
    }
}

// ---------------- GEMM: 1250 x 256-thr blocks; A staged once in LDS; 4 waves x 32 cols ----
// bf16x3 MFMA; ALPHAS epilogue via wa (wave 0). Frag maps per guide §3 (m89).

template <int NCOL, bool BIAS, bool ALPHAS>
__global__ __launch_bounds__(256)
void k_gemm2(const float* __restrict__ A, const ushort* __restrict__ wh,
             const ushort* __restrict__ wl, const float* __restrict__ bias,
             float* __restrict__ C, const float* __restrict__ wa,
             float* __restrict__ as_o, float* __restrict__ ad_o) {
    __shared__ float h[16][132];
    int t = threadIdx.x;
    int row0 = blockIdx.x * 16;
    for (int i = t; i < 512; i += 256) {
        int r = i >> 5, c4 = (i & 31) << 2;
        *(float4*)&h[r][c4] = *(const float4*)&A[(size_t)(row0 + r) * 128 + c4];
    }
    __syncthreads();

    int wid = t >> 6, l64 = t & 63;
    constexpr int CT = NCOL / 32;
    if (wid >= CT) return;
    int lr = l64 & 15, lg = l64 >> 4;
    int col0 = wid * 32;

    f32x4 af0[4], af1[4];
    #pragma unroll
    for (int s = 0; s < 4; s++) {
        af0[s] = *(const f32x4*)&h[lr][s * 32 + lg * 8];
        af1[s] = *(const f32x4*)&h[lr][s * 32 + lg * 8 + 4];
    }
    bf16x8 ah[4], al[4];
    #pragma unroll
    for (int s = 0; s < 4; s++) {
        #pragma unroll
        for (int j = 0; j < 8; j++) {
            float v = (j < 4) ? af0[s][j] : af1[s][j - 4];
            ushort hb = f2bf(v);
            float hf = __uint_as_float((uint)hb << 16);
            ah[s][j] = (short)hb;
            al[s][j] = (short)f2bf(v - hf);
        }
    }

    f32x4 acc[2] = {{0.f, 0.f, 0.f, 0.f}, {0.f, 0.f, 0.f, 0.f}};
    #pragma unroll
    for (int s = 0; s < 4; s++) {
        #pragma unroll
        for (int nt = 0; nt < 2; nt++) {
            int woff = (col0 + nt * 16 + lr) * 128 + s * 32 + lg * 8;
            bf16x8 bh = *(const bf16x8*)(wh + woff);
            bf16x8 bl = *(const bf16x8*)(wl + woff);
            acc[nt] = __builtin_amdgcn_mfma_f32_16x16x32_bf16(ah[s], bh, acc[nt], 0, 0, 0);
            acc[nt] = __builtin_amdgcn_mfma_f32_16x16x32_bf16(ah[s], bl, acc[nt], 0, 0, 0);
            acc[nt] = __builtin_amdgcn_mfma_f32_16x16x32_bf16(al[s], bh, acc[nt], 0, 0, 0);
        }
    }

    int orow = lg * 4;
    #pragma unroll
    for (int nt = 0; nt < 2; nt++) {
        int c = col0 + nt * 16 + lr;
        #pragma unroll
        for (int r = 0; r < 4; r++) {
            float v = acc[nt][r];
            if (BIAS) v += bias[c];
            C[(size_t)(row0 + orow + r) * NCOL + c] = v;
        }
    }

    if constexpr (ALPHAS) {
        if (wid == 0) {
            float ps = 0.f, pd = 0.f;
            #pragma unroll
            for (int s = 0; s < 4; s++) {
                #pragma unroll
                for (int j = 0; j < 8; j++) {
                    float v = (j < 4) ? af0[s][j] : af1[s][j - 4];
                    int k = s * 32 + lg * 8 + j;
                    ps += v * wa[k];
                    pd += v * wa[128 + k];
                }
            }
            ps += __shfl_xor(ps, 16);  pd += __shfl_xor(pd, 16);
            ps += __shfl_xor(ps, 32);  pd += __shfl_xor(pd, 32);
            if (lg == 0) {
                as_o[row0 + lr] = ps;
                ad_o[row0 + lr] = pd;
            }
        }
    }
}

// ---------------- launch ----------------

extern "C" void kernel_launch(void* const* d_in, const int* in_sizes, int n_in,
                              void* d_out, int out_size, void* d_ws, size_t ws_size,
                              hipStream_t stream) {
    const float* x      = (const float*)d_in[0];
    const int*   ei     = (const int*)d_in[1];
    const float* Ws     = (const float*)d_in[2];
    const float* attS   = (const float*)d_in[3];
    const float* attD   = (const float*)d_in[4];
    const float* biases = (const float*)d_in[5];
    const float* W_out  = (const float*)d_in[6];
    const float* b_out  = (const float*)d_in[7];
    float* out = (float*)d_out;

    const int* srcp = ei;
    const int* dstp = ei + EE;

    char* w = (char*)d_ws;
    auto take = [&](size_t bytes) {
        char* p = w;
        w += (bytes + 15) & ~(size_t)15;
        return p;
    };
    float*  za         = (float*)take((size_t)NN * HH * 4);
    float*  zbv        = (float*)take((size_t)NN * HH * 4);
    float*  hbuf       = (float*)take((size_t)NN * HH * 4);
    float*  asa        = (float*)take((size_t)NN * 4);
    float*  ada        = (float*)take((size_t)NN * 4);
    float*  asb        = (float*)take((size_t)NN * 4);
    float*  adb        = (float*)take((size_t)NN * 4);
    int*    counters   = (int*)take((size_t)NN * 4);
    int*    row_off    = (int*)take((size_t)(NN + 1) * 4);
    int*    cursor     = (int*)take((size_t)NN * 4);
    int*    src_sorted = (int*)take((size_t)ET * 4);
    int*    dst_sorted = (int*)take((size_t)ET * 4);
    float*  pbuf       = (float*)take((size_t)ET * 4);
    int*    partials   = (int*)take((size_t)NB * 4);
    int*    offsets    = (int*)take((size_t)NB * 4);
    const int WTOT = LL * HH * 128 + OO * 128;   // 73728
    ushort* whbuf      = (ushort*)take((size_t)WTOT * 2);
    ushort* wlbuf      = (ushort*)take((size_t)WTOT * 2);
    float*  wabuf      = (float*)take((size_t)LL * 256 * 4);

    // CSR build + weight prep
    k_init_counters<<<(NN + 255) / 256, 256, 0, stream>>>(counters);
    k_hist<<<(EE + 255) / 256, 256, 0, stream>>>(dstp, counters);
    k_partial<<<NB, 256, 0, stream>>>(counters, partials);
    k_scan_small<<<1, 128, 0, stream>>>(partials, offsets);
    k_apply<<<NB, 256, 0, stream>>>(counters, offsets, row_off, cursor,
                                    src_sorted, dst_sorted);
    k_scatter<<<(EE + 255) / 256, 256, 0, stream>>>(srcp, dstp, cursor,
                                                    src_sorted, dst_sorted);
    k_convw<<<(WTOT + 255) / 256, 256, 0, stream>>>(Ws, W_out, whbuf, wlbuf);
    k_wa<<<(LL * 256 + 255) / 256, 256, 0, stream>>>(Ws, attS, attD, wabuf);

    const int agg_blocks = (NN + 3) / 4;      // 5000
    const int ew_blocks  = (ET + 255) / 256;  // 2579

    // layer 0: z0 = x @ W0 (+alphas)
    k_gemm2<HH, false, true><<<NTILES, 256, 0, stream>>>(
        x, whbuf, wlbuf, nullptr, za, wabuf, asa, ada);

    // layers 1..3: ew + agg + gemm (+alphas), z double-buffer
    const float* zi[3]  = {za, zbv, za};
    float*       zo[3]  = {zbv, za, zbv};
    const float* asi[3] = {asa, asb, asa};
    const float* adi[3] = {ada, adb, ada};
    float*       aso[3] = {asb, asa, asb};
    float*       ado[3] = {adb, ada, adb};
    for (int l = 0; l < 3; l++) {
        k_ew<<<ew_blocks, 256, 0, stream>>>(asi[l], adi[l], src_sorted, dst_sorted, pbuf);
        k_agg<<<agg_blocks, 256, 0, stream>>>(zi[l], pbuf, row_off, src_sorted,
                                              biases + l * HH, hbuf);
        k_gemm2<HH, false, true><<<NTILES, 256, 0, stream>>>(
            hbuf, whbuf + (size_t)(l + 1) * HH * 128, wlbuf + (size_t)(l + 1) * HH * 128,
            nullptr, zo[l], wabuf + (l + 1) * 256, aso[l], ado[l]);
    }

    // final layer: ew + agg(z3) + out-projection with bias
    k_ew<<<ew_blocks, 256, 0, stream>>>(asb, adb, src_sorted, dst_sorted, pbuf);
    k_agg<<<agg_blocks, 256, 0, stream>>>(zbv, pbuf, row_off, src_sorted,
                                          biases + 3 * HH, hbuf);
    k_gemm2<OO, true, false><<<NTILES, 256, 0, stream>>>(
        hbuf, whbuf + (size_t)LL * HH * 128, wlbuf + (size_t)LL * HH * 128,
        b_out, out, nullptr, nullptr, nullptr);
}